// Round 12
// baseline (87.062 us; speedup 1.0000x reference)
//
#include <hip/hip_runtime.h>
#include <stdint.h>

#define BATCH 2048
#define INF 1024
#define OUTF 1024
#define GRID_G 8
#define KTOT 9216   // INF + INF*GRID_G

#define BM 256
#define BN 128
#define BK 32
#define SK 8
#define KC (KTOT / SK)   // 1152
#define NKT (KC / BK)    // 36
#define MT (BATCH / BM)  // 8
#define NT (OUTF / BN)   // 8
#define CSLAB ((size_t)BATCH * OUTF)

typedef __attribute__((ext_vector_type(8))) short short8_t;
typedef __attribute__((ext_vector_type(4))) float f32x4_t;
typedef __attribute__((ext_vector_type(8))) unsigned short u16x8_t;

__device__ __forceinline__ unsigned short f2bf(float f) {
  unsigned int u = __float_as_uint(f);
  u += 0x7FFFu + ((u >> 16) & 1u);
  return (unsigned short)(u >> 16);
}

__device__ __forceinline__ void async16(void* lds, const void* g) {
  __builtin_amdgcn_global_load_lds(
      (const __attribute__((address_space(1))) void*)g,
      (__attribute__((address_space(3))) void*)lds, 16, 0, 0);
}

// Build W_cat[o][k]: k<1024 -> bf16(base_weight[o][k]); else bf16(coeff[o][k-1024])
__global__ __launch_bounds__(256) void build_w_kernel(
    const float* __restrict__ bw, const float* __restrict__ coeff,
    unsigned short* __restrict__ wc) {
  int id = blockIdx.x * 256 + threadIdx.x;  // one thread per 8 elements
  int row = id / (KTOT / 8);
  int k8 = id - row * (KTOT / 8);
  int k = k8 * 8;
  const float* src = (k < INF) ? (bw + (size_t)row * INF + k)
                               : (coeff + (size_t)row * (INF * GRID_G) + (k - INF));
  const float4* s4 = (const float4*)src;
  float4 a = s4[0], b = s4[1];
  u16x8_t v;
  v[0] = f2bf(a.x); v[1] = f2bf(a.y); v[2] = f2bf(a.z); v[3] = f2bf(a.w);
  v[4] = f2bf(b.x); v[5] = f2bf(b.y); v[6] = f2bf(b.z); v[7] = f2bf(b.w);
  *(u16x8_t*)(wc + (size_t)id * 8) = v;
}

// Build A_cat[b][k]: k<1024 -> bf16(x[b][k]); spline block: one-hot(idx)*bf16(0.1*w)
__global__ __launch_bounds__(256) void build_a_kernel(
    const float* __restrict__ x, const float* __restrict__ grid,
    unsigned short* __restrict__ ac) {
  __shared__ float sg[GRID_G + 1];
  if (threadIdx.x <= GRID_G) sg[threadIdx.x] = grid[threadIdx.x];
  __syncthreads();
  int id = blockIdx.x * 256 + threadIdx.x;  // one per (b,i)
  int b = id >> 10;
  int i = id & 1023;
  float xv = x[id];
  ac[(size_t)b * KTOT + i] = f2bf(xv);
  float xc = fminf(fmaxf(xv, -1.0f), 1.0f);
  int cnt = 0;
#pragma unroll
  for (int j = 0; j <= GRID_G; ++j) cnt += (xc >= sg[j]) ? 1 : 0;
  int idx = cnt - 1;
  idx = idx < 0 ? 0 : (idx > GRID_G - 1 ? GRID_G - 1 : idx);
  float left = sg[idx], right = sg[idx + 1];
  float denom = right - left;
  denom = (denom == 0.0f) ? 1.0f : denom;
  float w = (xc - left) / denom;
  unsigned short val = f2bf(0.1f * w);
  u16x8_t v;
#pragma unroll
  for (int g = 0; g < GRID_G; ++g) v[g] = (g == idx) ? val : (unsigned short)0;
  *(u16x8_t*)(ac + (size_t)b * KTOT + INF + (size_t)i * 8) = v;
}

// 256x128xBK32 split-K GEMM: 8 waves (4m x 2n, 64x64 C each), 2 BLOCKS/CU
// (48 KB LDS, ~64 VGPR + 64 AGPR acc per lane) -> cross-block latency hiding
// (R4's proven mechanism) AND 2.7x R4's MFMA-per-staged-byte ratio.
// Loop = R4's empirically-best order: sync; stage(next); ds_read(cur); MFMA.
// Chunk-transposed 1KB LDS units (16 rows x 4 chunks, phys chunk = k*16+r):
// ds_read_b128 conflict-free (verified 0 in R6-R11).
__global__ __launch_bounds__(512, 4) void gemm_kernel(
    const unsigned short* __restrict__ A, const unsigned short* __restrict__ W,
    unsigned short* __restrict__ P) {
  __shared__ unsigned short As[2][BM * BK];  // 2 x 16 KB
  __shared__ unsigned short Bs[2][BN * BK];  // 2 x  8 KB

  int bid = blockIdx.x;
  int sk = bid & 7;            // XCD affinity: one sk-slab per XCD
  int t0 = bid >> 3;           // 0..63
  int mt = t0 >> 3;            // 0..7
  int nt = t0 & 7;             // 0..7

  int tid = threadIdx.x, wave = tid >> 6, lane = tid & 63;
  int wm = wave >> 1, wn = wave & 1;   // 4x2 wave grid, 64x64 C per wave
  int lr = lane & 15, lk = lane >> 4;
  int rlo = lk * 128 + lr * 8;         // chunk-transposed intra-unit offset

  // staging source (chunk-transpose): lane l -> row +(l&15), chunk l>>4
  // A: wave covers rows 32w..32w+31 (units 2w, 2w+1); B: rows 16w.. (unit w)
  int scol = (lane >> 4) * 8;
  const unsigned short* gA  = A + (size_t)(mt * BM + wave * 32 + (lane & 15)) * KTOT + sk * KC + scol;
  const unsigned short* gA2 = gA + (size_t)16 * KTOT;
  const unsigned short* gB  = W + (size_t)(nt * BN + wave * 16 + (lane & 15)) * KTOT + sk * KC + scol;

  f32x4_t acc[4][4];
#pragma unroll
  for (int i2 = 0; i2 < 4; ++i2)
#pragma unroll
    for (int j2 = 0; j2 < 4; ++j2) acc[i2][j2] = f32x4_t{0.0f, 0.0f, 0.0f, 0.0f};

#define STAGE_AB(bf_, tt) { \
    int ko_ = (tt) * BK; \
    unsigned short* da_ = &As[bf_][wave * 1024]; \
    async16(da_, gA + ko_); \
    async16(da_ + 512, gA2 + ko_); \
    async16(&Bs[bf_][wave * 512], gB + ko_); }

  STAGE_AB(0, 0)

  for (int t = 0; t < NKT; ++t) {
    int cur = t & 1;
    __syncthreads();                       // drains stage(t); WAR-safe
    if (t + 1 < NKT) STAGE_AB(cur ^ 1, t + 1)

    short8_t af[4], bf[4];
#pragma unroll
    for (int mi = 0; mi < 4; ++mi)
      af[mi] = *(const short8_t*)&As[cur][(wm * 4 + mi) * 512 + rlo];
#pragma unroll
    for (int ni = 0; ni < 4; ++ni)
      bf[ni] = *(const short8_t*)&Bs[cur][(wn * 4 + ni) * 512 + rlo];

    __builtin_amdgcn_s_setprio(1);
#pragma unroll
    for (int mi = 0; mi < 4; ++mi)
#pragma unroll
      for (int ni = 0; ni < 4; ++ni)
        acc[mi][ni] = __builtin_amdgcn_mfma_f32_16x16x32_bf16(af[mi], bf[ni], acc[mi][ni], 0, 0, 0);
    __builtin_amdgcn_s_setprio(0);
  }

  // epilogue: C/D col=lane&15 (n), row=(lane>>4)*4+reg (m); private bf16 slab
  unsigned short* slab = P + (size_t)sk * CSLAB;
#pragma unroll
  for (int mi = 0; mi < 4; ++mi) {
#pragma unroll
    for (int ni = 0; ni < 4; ++ni) {
      int col = nt * BN + wn * 64 + ni * 16 + lr;
#pragma unroll
      for (int r = 0; r < 4; ++r) {
        int rowm = mt * BM + wm * 64 + mi * 16 + lk * 4 + r;
        slab[(size_t)rowm * OUTF + col] = f2bf(acc[mi][ni][r]);
      }
    }
  }
}

// out[e] = sum_sk P[sk][e]; 8 elements/thread, fully overwrites d_out.
__global__ __launch_bounds__(256) void reduce_kernel(
    const unsigned short* __restrict__ P, float* __restrict__ out) {
  size_t base = ((size_t)blockIdx.x * 256 + threadIdx.x) * 8;
  float s[8];
#pragma unroll
  for (int j = 0; j < 8; ++j) s[j] = 0.0f;
#pragma unroll
  for (int k = 0; k < SK; ++k) {
    u16x8_t v = *(const u16x8_t*)(P + (size_t)k * CSLAB + base);
#pragma unroll
    for (int j = 0; j < 8; ++j)
      s[j] += __uint_as_float((unsigned int)v[j] << 16);
  }
  float4 lo = {s[0], s[1], s[2], s[3]};
  float4 hi = {s[4], s[5], s[6], s[7]};
  *(float4*)(out + base) = lo;
  *(float4*)(out + base + 4) = hi;
}

extern "C" void kernel_launch(void* const* d_in, const int* in_sizes, int n_in,
                              void* d_out, int out_size, void* d_ws, size_t ws_size,
                              hipStream_t stream) {
  const float* x = (const float*)d_in[0];
  const float* bw = (const float*)d_in[1];
  const float* coeff = (const float*)d_in[2];
  const float* grid = (const float*)d_in[3];
  float* out = (float*)d_out;

  unsigned short* Acat = (unsigned short*)d_ws;              // 37.75 MB
  unsigned short* Wcat = Acat + (size_t)BATCH * KTOT;        // 18.87 MB
  unsigned short* Part = Wcat + (size_t)OUTF * KTOT;         // 33.55 MB

  build_w_kernel<<<OUTF * (KTOT / 8) / 256, 256, 0, stream>>>(bw, coeff, Wcat);
  build_a_kernel<<<BATCH * INF / 256, 256, 0, stream>>>(x, grid, Acat);
  gemm_kernel<<<SK * MT * NT, 512, 0, stream>>>(Acat, Wcat, Part);
  reduce_kernel<<<(int)(CSLAB / 8 / 256), 256, 0, stream>>>(Part, out);
}

// Round 13
// 86.739 us; speedup vs baseline: 1.0037x; 1.0037x over previous
//
#include <hip/hip_runtime.h>
#include <stdint.h>

#define BATCH 2048
#define INF 1024
#define OUTF 1024
#define GRID_G 8
#define KTOT 9216   // INF + INF*GRID_G

#define BM 256
#define BN 128
#define BK 32
#define SK 8
#define KC (KTOT / SK)   // 1152
#define NKT (KC / BK)    // 36
#define MT (BATCH / BM)  // 8
#define NT (OUTF / BN)   // 8
#define CSLAB ((size_t)BATCH * OUTF)

typedef __attribute__((ext_vector_type(8))) short short8_t;
typedef __attribute__((ext_vector_type(4))) float f32x4_t;
typedef __attribute__((ext_vector_type(8))) unsigned short u16x8_t;

__device__ __forceinline__ unsigned short f2bf(float f) {
  unsigned int u = __float_as_uint(f);
  u += 0x7FFFu + ((u >> 16) & 1u);
  return (unsigned short)(u >> 16);
}

__device__ __forceinline__ void async16(void* lds, const void* g) {
  __builtin_amdgcn_global_load_lds(
      (const __attribute__((address_space(1))) void*)g,
      (__attribute__((address_space(3))) void*)lds, 16, 0, 0);
}

// Build W_cat[o][k]: k<1024 -> bf16(base_weight[o][k]); else bf16(coeff[o][k-1024])
__global__ __launch_bounds__(256) void build_w_kernel(
    const float* __restrict__ bw, const float* __restrict__ coeff,
    unsigned short* __restrict__ wc) {
  int id = blockIdx.x * 256 + threadIdx.x;  // one thread per 8 elements
  int row = id / (KTOT / 8);
  int k8 = id - row * (KTOT / 8);
  int k = k8 * 8;
  const float* src = (k < INF) ? (bw + (size_t)row * INF + k)
                               : (coeff + (size_t)row * (INF * GRID_G) + (k - INF));
  const float4* s4 = (const float4*)src;
  float4 a = s4[0], b = s4[1];
  u16x8_t v;
  v[0] = f2bf(a.x); v[1] = f2bf(a.y); v[2] = f2bf(a.z); v[3] = f2bf(a.w);
  v[4] = f2bf(b.x); v[5] = f2bf(b.y); v[6] = f2bf(b.z); v[7] = f2bf(b.w);
  *(u16x8_t*)(wc + (size_t)id * 8) = v;
}

// Build A_cat[b][k]: k<1024 -> bf16(x[b][k]); spline block: one-hot(idx)*bf16(0.1*w)
__global__ __launch_bounds__(256) void build_a_kernel(
    const float* __restrict__ x, const float* __restrict__ grid,
    unsigned short* __restrict__ ac) {
  __shared__ float sg[GRID_G + 1];
  if (threadIdx.x <= GRID_G) sg[threadIdx.x] = grid[threadIdx.x];
  __syncthreads();
  int id = blockIdx.x * 256 + threadIdx.x;  // one per (b,i)
  int b = id >> 10;
  int i = id & 1023;
  float xv = x[id];
  ac[(size_t)b * KTOT + i] = f2bf(xv);
  float xc = fminf(fmaxf(xv, -1.0f), 1.0f);
  int cnt = 0;
#pragma unroll
  for (int j = 0; j <= GRID_G; ++j) cnt += (xc >= sg[j]) ? 1 : 0;
  int idx = cnt - 1;
  idx = idx < 0 ? 0 : (idx > GRID_G - 1 ? GRID_G - 1 : idx);
  float left = sg[idx], right = sg[idx + 1];
  float denom = right - left;
  denom = (denom == 0.0f) ? 1.0f : denom;
  float w = (xc - left) / denom;
  unsigned short val = f2bf(0.1f * w);
  u16x8_t v;
#pragma unroll
  for (int g = 0; g < GRID_G; ++g) v[g] = (g == idx) ? val : (unsigned short)0;
  *(u16x8_t*)(ac + (size_t)b * KTOT + INF + (size_t)i * 8) = v;
}

// 256x128xBK32 split-K GEMM. 4 waves/block (2x2 grid of 128x64 WAVE-tiles:
// 384 B of ds_read per MFMA = 4.5 cyc/MFMA < 4.85 MFMA cyc -> NOT LDS-bound,
// unlike all 64x64-wave-tile variants at 512 B/MFMA = 6.0 cyc) x 2 independent
// blocks/CU (48 KB LDS dbuf; ~116 VGPR precedent from R5's identical per-wave
// shape) for cross-block latency hiding. R4's proven loop order.
// Chunk-transposed 1KB LDS units: ds_read_b128 conflict-free (0 in R6-R12).
__global__ __launch_bounds__(256, 2) void gemm_kernel(
    const unsigned short* __restrict__ A, const unsigned short* __restrict__ W,
    unsigned short* __restrict__ P) {
  __shared__ unsigned short As[2][BM * BK];  // 2 x 16 KB
  __shared__ unsigned short Bs[2][BN * BK];  // 2 x  8 KB

  int bid = blockIdx.x;
  int sk = bid & 7;            // XCD affinity: one sk-slab per XCD
  int t0 = bid >> 3;           // 0..63
  int mt = t0 >> 3;            // 0..7
  int nt = t0 & 7;             // 0..7

  int tid = threadIdx.x, wave = tid >> 6, lane = tid & 63;
  int wm = wave >> 1, wn = wave & 1;   // 2x2 wave grid, 128x64 C per wave
  int lr = lane & 15, lk = lane >> 4;
  int rlo = lk * 128 + lr * 8;         // chunk-transposed intra-unit offset

  // staging source (chunk-transpose): lane l -> row +(l&15), chunk l>>4.
  // A: wave w owns units 4w..4w+3 (rows 64w..64w+63); B: units 2w..2w+1.
  int scol = (lane >> 4) * 8;
  const unsigned short* gA = A + (size_t)(mt * BM + wave * 64 + (lane & 15)) * KTOT + sk * KC + scol;
  const unsigned short* gB = W + (size_t)(nt * BN + wave * 32 + (lane & 15)) * KTOT + sk * KC + scol;
  const size_t r16 = (size_t)16 * KTOT;

  f32x4_t acc[8][4];
#pragma unroll
  for (int i2 = 0; i2 < 8; ++i2)
#pragma unroll
    for (int j2 = 0; j2 < 4; ++j2) acc[i2][j2] = f32x4_t{0.0f, 0.0f, 0.0f, 0.0f};

#define STAGE_AB(bf_, tt) { \
    int ko_ = (tt) * BK; \
    unsigned short* da_ = &As[bf_][wave * 2048]; \
    async16(da_,        gA + ko_); \
    async16(da_ + 512,  gA + r16 + ko_); \
    async16(da_ + 1024, gA + 2 * r16 + ko_); \
    async16(da_ + 1536, gA + 3 * r16 + ko_); \
    unsigned short* db_ = &Bs[bf_][wave * 1024]; \
    async16(db_,       gB + ko_); \
    async16(db_ + 512, gB + r16 + ko_); }

  STAGE_AB(0, 0)

  for (int t = 0; t < NKT; ++t) {
    int cur = t & 1;
    __syncthreads();                       // drains stage(t); WAR-safe
    if (t + 1 < NKT) STAGE_AB(cur ^ 1, t + 1)

    short8_t bf[4];
#pragma unroll
    for (int ni = 0; ni < 4; ++ni)
      bf[ni] = *(const short8_t*)&Bs[cur][(wn * 4 + ni) * 512 + rlo];
    short8_t af[8];
#pragma unroll
    for (int mi = 0; mi < 8; ++mi)
      af[mi] = *(const short8_t*)&As[cur][(wm * 8 + mi) * 512 + rlo];

    __builtin_amdgcn_s_setprio(1);
#pragma unroll
    for (int mi = 0; mi < 8; ++mi)
#pragma unroll
      for (int ni = 0; ni < 4; ++ni)
        acc[mi][ni] = __builtin_amdgcn_mfma_f32_16x16x32_bf16(af[mi], bf[ni], acc[mi][ni], 0, 0, 0);
    __builtin_amdgcn_s_setprio(0);
  }

  // epilogue: C/D col=lane&15 (n), row=(lane>>4)*4+reg (m); private bf16 slab
  unsigned short* slab = P + (size_t)sk * CSLAB;
#pragma unroll
  for (int mi = 0; mi < 8; ++mi) {
#pragma unroll
    for (int ni = 0; ni < 4; ++ni) {
      int col = nt * BN + wn * 64 + ni * 16 + lr;
#pragma unroll
      for (int r = 0; r < 4; ++r) {
        int rowm = mt * BM + wm * 128 + mi * 16 + lk * 4 + r;
        slab[(size_t)rowm * OUTF + col] = f2bf(acc[mi][ni][r]);
      }
    }
  }
}

// out[e] = sum_sk P[sk][e]; 8 elements/thread, fully overwrites d_out.
__global__ __launch_bounds__(256) void reduce_kernel(
    const unsigned short* __restrict__ P, float* __restrict__ out) {
  size_t base = ((size_t)blockIdx.x * 256 + threadIdx.x) * 8;
  float s[8];
#pragma unroll
  for (int j = 0; j < 8; ++j) s[j] = 0.0f;
#pragma unroll
  for (int k = 0; k < SK; ++k) {
    u16x8_t v = *(const u16x8_t*)(P + (size_t)k * CSLAB + base);
#pragma unroll
    for (int j = 0; j < 8; ++j)
      s[j] += __uint_as_float((unsigned int)v[j] << 16);
  }
  float4 lo = {s[0], s[1], s[2], s[3]};
  float4 hi = {s[4], s[5], s[6], s[7]};
  *(float4*)(out + base) = lo;
  *(float4*)(out + base + 4) = hi;
}

extern "C" void kernel_launch(void* const* d_in, const int* in_sizes, int n_in,
                              void* d_out, int out_size, void* d_ws, size_t ws_size,
                              hipStream_t stream) {
  const float* x = (const float*)d_in[0];
  const float* bw = (const float*)d_in[1];
  const float* coeff = (const float*)d_in[2];
  const float* grid = (const float*)d_in[3];
  float* out = (float*)d_out;

  unsigned short* Acat = (unsigned short*)d_ws;              // 37.75 MB
  unsigned short* Wcat = Acat + (size_t)BATCH * KTOT;        // 18.87 MB
  unsigned short* Part = Wcat + (size_t)OUTF * KTOT;         // 33.55 MB

  build_w_kernel<<<OUTF * (KTOT / 8) / 256, 256, 0, stream>>>(bw, coeff, Wcat);
  build_a_kernel<<<BATCH * INF / 256, 256, 0, stream>>>(x, grid, Acat);
  gemm_kernel<<<SK * MT * NT, 256, 0, stream>>>(Acat, Wcat, Part);
  reduce_kernel<<<(int)(CSLAB / 8 / 256), 256, 0, stream>>>(Part, out);
}